// Round 1
// baseline (158.300 us; speedup 1.0000x reference)
//
#include <hip/hip_runtime.h>

typedef short short8 __attribute__((ext_vector_type(8)));
typedef float f32x4 __attribute__((ext_vector_type(4)));

// ---------------- ws layout (bytes) ----------------
// A_pack : v in MFMA A-fragment order  [1024 mtile][16 kstep][64 lane][8] bf16
// B1_pack: first-layer weights         [3 branch][16 ks][10 nt][64][8] bf16
// B2_pack: second-layer weights        [6 eid][2 kk][2 nt][64][8] bf16
// B3_pack: third-layer weights         [6 eid][4 nt][64][8] bf16
enum : unsigned {
  OFF_A   = 0u,
  OFF_B1  = 16777216u,
  OFF_B2  = 17268736u,
  OFF_B3  = 17293312u,
  OFF_b1  = 17317888u,   // [3][160] f32 (expert0 b1 | expert1 b1 | gate b1)
  OFF_b2  = 17319808u,   // [6][32] f32
  OFF_b3  = 17320576u,   // [6][64] f32
  OFF_gam = 17322112u,   // [6][64] f32
  OFF_bet = 17323648u,   // [6][64] f32
  OFF_gw2 = 17325184u,   // [3][32][2] f32
  OFF_gb2 = 17325952u    // [3][2] f32
};

__device__ __forceinline__ unsigned short f2bf(float x) {
  unsigned u = __builtin_bit_cast(unsigned, x);
  return (unsigned short)((u + 0x7fffu + ((u >> 16) & 1u)) >> 16);
}
__device__ __forceinline__ float bf2f(unsigned short b) {
  unsigned u = ((unsigned)b) << 16;
  return __builtin_bit_cast(float, u);
}
__device__ __forceinline__ float silu(float x) { return x / (1.f + __expf(-x)); }
// assumed k-slot map for 16x16x32 frags; consistent between A and B packs so any
// hw permutation cancels.
__device__ __forceinline__ int fragk(int lane, int j) {
  return ((lane >> 4) << 2) + (j & 3) + ((j >> 2) << 4);
}

// ---------------- pack v into A-fragment order ----------------
__global__ void pack_A(const float* __restrict__ v, unsigned char* __restrict__ ws) {
  int t = blockIdx.x * blockDim.x + threadIdx.x;   // 0..1048575 exact
  int lane = t & 63, ks = (t >> 6) & 15, mtile = t >> 10;
  int row = mtile * 16 + (lane & 15);
  int k0  = ks * 32 + ((lane >> 4) << 2);
  const float* base = v + row * 512 + k0;
  float4 lo = *(const float4*)base;
  float4 hi = *(const float4*)(base + 16);
  short8 o;
  o[0] = (short)f2bf(lo.x); o[1] = (short)f2bf(lo.y);
  o[2] = (short)f2bf(lo.z); o[3] = (short)f2bf(lo.w);
  o[4] = (short)f2bf(hi.x); o[5] = (short)f2bf(hi.y);
  o[6] = (short)f2bf(hi.z); o[7] = (short)f2bf(hi.w);
  ((short8*)(ws + OFF_A))[t] = o;
}

// ---------------- pack all weights/biases ----------------
__global__ void pack_W(
    const float* __restrict__ sw1, const float* __restrict__ sb1,
    const float* __restrict__ sw2, const float* __restrict__ sb2,
    const float* __restrict__ sw3, const float* __restrict__ sb3,
    const float* __restrict__ sgam, const float* __restrict__ sbet,
    const float* __restrict__ sgw1, const float* __restrict__ sgb1,
    const float* __restrict__ sgw2, const float* __restrict__ sgb2,
    const float* __restrict__ gw1, const float* __restrict__ gb1,
    const float* __restrict__ gw2, const float* __restrict__ gb2,
    const float* __restrict__ gw3, const float* __restrict__ gb3,
    const float* __restrict__ ggam, const float* __restrict__ gbet,
    const float* __restrict__ ggw1, const float* __restrict__ ggb1,
    const float* __restrict__ ggw2, const float* __restrict__ ggb2,
    unsigned char* __restrict__ ws) {
  int id = blockIdx.x * blockDim.x + threadIdx.x;

  if (id < 30720) {              // B1 fragment groups
    int lane = id & 63; int rest = id >> 6;     // (branch*16+ks)*10+nt
    int nt = rest % 10; int rk = rest / 10;
    int ks = rk & 15; int branch = rk >> 4;
    int col = nt * 16 + (lane & 15);
    short8 o;
#pragma unroll
    for (int j = 0; j < 8; ++j) {
      int k = ks * 32 + fragk(lane, j);
      float w;
      if (branch < 2) {
        if (col < 128) w = gw1[((branch * 2 + (col >> 6)) * 512 + k) * 64 + (col & 63)];
        else           w = ggw1[(branch * 512 + k) * 32 + (col - 128)];
      } else {
        if (col < 128) w = sw1[((col >> 6) * 512 + k) * 64 + (col & 63)];
        else           w = sgw1[k * 32 + (col - 128)];
      }
      o[j] = (short)f2bf(w);
    }
    ((short8*)(ws + OFF_B1))[id] = o;
    return;
  }
  id -= 30720;
  if (id < 1536) {               // B2
    int lane = id & 63; int rest = id >> 6;     // eid*4 + kk*2 + nt
    int nt = rest & 1, kk = (rest >> 1) & 1, eid = rest >> 2;
    int n = nt * 16 + (lane & 15);
    short8 o;
#pragma unroll
    for (int j = 0; j < 8; ++j) {
      int k = kk * 32 + fragk(lane, j);
      float w = (eid < 4) ? gw2[(eid * 64 + k) * 32 + n] : sw2[((eid - 4) * 64 + k) * 32 + n];
      o[j] = (short)f2bf(w);
    }
    ((short8*)(ws + OFF_B2))[id] = o;
    return;
  }
  id -= 1536;
  if (id < 1536) {               // B3
    int lane = id & 63; int rest = id >> 6;     // eid*4 + nt
    int nt = rest & 3, eid = rest >> 2;
    int n = nt * 16 + (lane & 15);
    short8 o;
#pragma unroll
    for (int j = 0; j < 8; ++j) {
      int k = fragk(lane, j);                   // < 32
      float w = (eid < 4) ? gw3[(eid * 32 + k) * 64 + n] : sw3[((eid - 4) * 32 + k) * 64 + n];
      o[j] = (short)f2bf(w);
    }
    ((short8*)(ws + OFF_B3))[id] = o;
    return;
  }
  id -= 1536;
  if (id < 480) {                // b1cat [3][160]
    int branch = id / 160, col = id % 160;
    float w;
    if (col < 128) w = (branch < 2) ? gb1[(branch * 2 + (col >> 6)) * 64 + (col & 63)]
                                    : sb1[(col >> 6) * 64 + (col & 63)];
    else           w = (branch < 2) ? ggb1[branch * 32 + (col - 128)] : sgb1[col - 128];
    ((float*)(ws + OFF_b1))[id] = w;
    return;
  }
  id -= 480;
  if (id < 192) { ((float*)(ws + OFF_b2))[id] = (id < 128) ? gb2[id] : sb2[id - 128]; return; }
  id -= 192;
  if (id < 384) { ((float*)(ws + OFF_b3))[id] = (id < 256) ? gb3[id] : sb3[id - 256]; return; }
  id -= 384;
  if (id < 384) { ((float*)(ws + OFF_gam))[id] = (id < 256) ? ggam[id] : sgam[id - 256]; return; }
  id -= 384;
  if (id < 384) { ((float*)(ws + OFF_bet))[id] = (id < 256) ? gbet[id] : sbet[id - 256]; return; }
  id -= 384;
  if (id < 192) { int branch = id / 64; ((float*)(ws + OFF_gw2))[id] = (branch < 2) ? ggw2[id] : sgw2[id % 64]; return; }
  id -= 192;
  if (id < 6)  { ((float*)(ws + OFF_gb2))[id] = (id < 4) ? ggb2[id] : sgb2[id % 2]; return; }
}

// ---------------- fused main kernel ----------------
// grid (256, 3): blockIdx.x -> 64-row block (4 waves x 16 rows), blockIdx.y -> branch
__global__ __launch_bounds__(256) void home_main(const unsigned char* __restrict__ ws,
                                                 float* __restrict__ out) {
  const int lane = threadIdx.x & 63, wave = threadIdx.x >> 6;
  const int branch = blockIdx.y;
  const int mtile = blockIdx.x * 4 + wave;          // 16-row tile, 0..1023
  const int col16 = lane & 15, g4 = lane >> 4;

  const short8* Ap = (const short8*)(ws + OFF_A);
  const short8* B1 = (const short8*)(ws + OFF_B1);
  const short8* B2 = (const short8*)(ws + OFF_B2);
  const short8* B3 = (const short8*)(ws + OFF_B3);
  const float* b1c  = (const float*)(ws + OFF_b1) + branch * 160;
  const float* b2c  = (const float*)(ws + OFF_b2);
  const float* b3c  = (const float*)(ws + OFF_b3);
  const float* gamc = (const float*)(ws + OFF_gam);
  const float* betc = (const float*)(ws + OFF_bet);
  const float* gw2c = (const float*)(ws + OFF_gw2) + branch * 64;
  const float* gb2c = (const float*)(ws + OFF_gb2) + branch * 2;

  __shared__ unsigned short h1l[4][16][164];   // padded: conflict-free frag reads
  __shared__ unsigned short h2l[4][16][68];
  __shared__ float gatew[4][16][2];

  // ---- stage 1: [16 x 512] @ [512 x 160] ----
  f32x4 acc[10];
#pragma unroll
  for (int nt = 0; nt < 10; ++nt) acc[nt] = (f32x4){0.f, 0.f, 0.f, 0.f};

#pragma unroll 2
  for (int ks = 0; ks < 16; ++ks) {
    short8 a = Ap[(mtile * 16 + ks) * 64 + lane];
#pragma unroll
    for (int nt = 0; nt < 10; ++nt) {
      short8 b = B1[((branch * 16 + ks) * 10 + nt) * 64 + lane];
      acc[nt] = __builtin_amdgcn_mfma_f32_16x16x32_bf16(a, b, acc[nt], 0, 0, 0);
    }
  }

  // bias + silu -> LDS (bf16), D layout: col=lane&15, row=4*(lane>>4)+reg
#pragma unroll
  for (int nt = 0; nt < 10; ++nt) {
    int col = nt * 16 + col16;
    float bb = b1c[col];
#pragma unroll
    for (int r = 0; r < 4; ++r) {
      int row = (g4 << 2) + r;
      h1l[wave][row][col] = f2bf(silu(acc[nt][r] + bb));
    }
  }
  __syncthreads();

  // ---- gate: logits from silu'd hidden (cols 128..159), softmax over 2 ----
  {
    int rowg = (lane >> 1) & 15;
    int e = lane & 1;
    float logit = gb2c[e];
#pragma unroll 8
    for (int j = 0; j < 32; ++j)
      logit += bf2f(h1l[wave][rowg][128 + j]) * gw2c[j * 2 + e];
    float other = __shfl_xor(logit, 1, 64);
    float mx = fmaxf(logit, other);
    float a0 = __expf(logit - mx), a1 = __expf(other - mx);
    if (lane < 32) gatew[wave][rowg][e] = a0 / (a0 + a1);
  }

  // ---- stage 2: per expert [16 x 64] @ [64 x 32], silu -> LDS ----
#pragma unroll
  for (int e2 = 0; e2 < 2; ++e2) {
    const int eid = (branch < 2) ? branch * 2 + e2 : 4 + e2;
    f32x4 a2[2];
    a2[0] = (f32x4){0.f, 0.f, 0.f, 0.f};
    a2[1] = (f32x4){0.f, 0.f, 0.f, 0.f};
#pragma unroll
    for (int kk = 0; kk < 2; ++kk) {
      const unsigned short* p = &h1l[wave][col16][e2 * 64 + kk * 32 + (g4 << 2)];
      union { short8 s; unsigned u[4]; } af;
      af.u[0] = *(const unsigned*)p;        af.u[1] = *(const unsigned*)(p + 2);
      af.u[2] = *(const unsigned*)(p + 16); af.u[3] = *(const unsigned*)(p + 18);
#pragma unroll
      for (int nt = 0; nt < 2; ++nt) {
        short8 b = B2[((eid * 2 + kk) * 2 + nt) * 64 + lane];
        a2[nt] = __builtin_amdgcn_mfma_f32_16x16x32_bf16(af.s, b, a2[nt], 0, 0, 0);
      }
    }
#pragma unroll
    for (int nt = 0; nt < 2; ++nt) {
      int c2 = nt * 16 + col16;
      float bb = b2c[eid * 32 + c2];
#pragma unroll
      for (int r = 0; r < 4; ++r) {
        int row = (g4 << 2) + r;
        h2l[wave][row][e2 * 32 + c2] = f2bf(silu(a2[nt][r] + bb));
      }
    }
  }
  __syncthreads();

  // ---- stage 3: per expert [16 x 32] @ [32 x 64], LN, gated combine ----
  float z[4][4];
#pragma unroll
  for (int r = 0; r < 4; ++r)
#pragma unroll
    for (int nt = 0; nt < 4; ++nt) z[r][nt] = 0.f;

#pragma unroll
  for (int e2 = 0; e2 < 2; ++e2) {
    const int eid = (branch < 2) ? branch * 2 + e2 : 4 + e2;
    f32x4 a3[4];
#pragma unroll
    for (int nt = 0; nt < 4; ++nt) a3[nt] = (f32x4){0.f, 0.f, 0.f, 0.f};
    const unsigned short* p = &h2l[wave][col16][e2 * 32 + (g4 << 2)];
    union { short8 s; unsigned u[4]; } af;
    af.u[0] = *(const unsigned*)p;        af.u[1] = *(const unsigned*)(p + 2);
    af.u[2] = *(const unsigned*)(p + 16); af.u[3] = *(const unsigned*)(p + 18);
#pragma unroll
    for (int nt = 0; nt < 4; ++nt) {
      short8 b = B3[(eid * 4 + nt) * 64 + lane];
      a3[nt] = __builtin_amdgcn_mfma_f32_16x16x32_bf16(af.s, b, a3[nt], 0, 0, 0);
    }
#pragma unroll
    for (int r = 0; r < 4; ++r) {
      float o[4], s = 0.f, s2 = 0.f;
#pragma unroll
      for (int nt = 0; nt < 4; ++nt) {
        o[nt] = a3[nt][r] + b3c[eid * 64 + nt * 16 + col16];
        s += o[nt]; s2 += o[nt] * o[nt];
      }
#pragma unroll
      for (int m = 1; m < 16; m <<= 1) {
        s  += __shfl_xor(s, m, 64);
        s2 += __shfl_xor(s2, m, 64);
      }
      float mu  = s * 0.015625f;
      float var = s2 * 0.015625f - mu * mu;
      float inv = rsqrtf(var + 1e-5f);
      int row = (g4 << 2) + r;
      float wt = gatew[wave][row][e2];
#pragma unroll
      for (int nt = 0; nt < 4; ++nt) {
        int c = nt * 16 + col16;
        float ln = (o[nt] - mu) * inv * gamc[eid * 64 + c] + betc[eid * 64 + c];
        z[r][nt] += wt * ln;
      }
    }
  }

#pragma unroll
  for (int r = 0; r < 4; ++r) {
    int grow = mtile * 16 + (g4 << 2) + r;
#pragma unroll
    for (int nt = 0; nt < 4; ++nt)
      out[(branch * 16384 + grow) * 64 + nt * 16 + col16] = z[r][nt];
  }
}

extern "C" void kernel_launch(void* const* d_in, const int* in_sizes, int n_in,
                              void* d_out, int out_size, void* d_ws, size_t ws_size,
                              hipStream_t stream) {
  const float* v    = (const float*)d_in[0];
  const float* sw1  = (const float*)d_in[1];
  const float* sb1  = (const float*)d_in[2];
  const float* sw2  = (const float*)d_in[3];
  const float* sb2  = (const float*)d_in[4];
  const float* sw3  = (const float*)d_in[5];
  const float* sb3  = (const float*)d_in[6];
  const float* sgam = (const float*)d_in[7];
  const float* sbet = (const float*)d_in[8];
  const float* sgw1 = (const float*)d_in[9];
  const float* sgb1 = (const float*)d_in[10];
  const float* sgw2 = (const float*)d_in[11];
  const float* sgb2 = (const float*)d_in[12];
  const float* gw1  = (const float*)d_in[13];
  const float* gb1  = (const float*)d_in[14];
  const float* gw2  = (const float*)d_in[15];
  const float* gb2  = (const float*)d_in[16];
  const float* gw3  = (const float*)d_in[17];
  const float* gb3  = (const float*)d_in[18];
  const float* ggam = (const float*)d_in[19];
  const float* gbet = (const float*)d_in[20];
  const float* ggw1 = (const float*)d_in[21];
  const float* ggb1 = (const float*)d_in[22];
  const float* ggw2 = (const float*)d_in[23];
  const float* ggb2 = (const float*)d_in[24];
  unsigned char* ws = (unsigned char*)d_ws;
  float* out = (float*)d_out;

  pack_A<<<dim3(4096), dim3(256), 0, stream>>>(v, ws);
  pack_W<<<dim3(140), dim3(256), 0, stream>>>(
      sw1, sb1, sw2, sb2, sw3, sb3, sgam, sbet, sgw1, sgb1, sgw2, sgb2,
      gw1, gb1, gw2, gb2, gw3, gb3, ggam, gbet, ggw1, ggb1, ggw2, ggb2, ws);
  home_main<<<dim3(256, 3), dim3(256), 0, stream>>>(ws, out);
}

// Round 2
// 143.555 us; speedup vs baseline: 1.1027x; 1.1027x over previous
//
#include <hip/hip_runtime.h>

typedef short short8 __attribute__((ext_vector_type(8)));
typedef float f32x4 __attribute__((ext_vector_type(4)));

// ---------------- ws layout (bytes) ----------------
// B1_pack: first-layer weights [3 branch][16 ks][10 nt][64 lane][8] bf16
// B2_pack: second-layer weights [6 eid][2 kk][2 nt][64][8] bf16
// B3_pack: third-layer weights  [6 eid][4 nt][64][8] bf16
enum : unsigned {
  OFF_B1  = 0u,
  OFF_B2  = 491520u,
  OFF_B3  = 516096u,
  OFF_b1  = 540672u,   // [3][160] f32 (expert0 b1 | expert1 b1 | gate b1)
  OFF_b2  = 542592u,   // [6][32] f32
  OFF_b3  = 543360u,   // [6][64] f32
  OFF_gam = 544896u,   // [6][64] f32
  OFF_bet = 546432u,   // [6][64] f32
  OFF_gw2 = 547968u,   // [3][32][2] f32
  OFF_gb2 = 548736u    // [3][2] f32
};

__device__ __forceinline__ unsigned short f2bf(float x) {
  unsigned u = __builtin_bit_cast(unsigned, x);
  return (unsigned short)((u + 0x7fffu + ((u >> 16) & 1u)) >> 16);
}
__device__ __forceinline__ float bf2f(unsigned short b) {
  unsigned u = ((unsigned)b) << 16;
  return __builtin_bit_cast(float, u);
}
__device__ __forceinline__ float silu(float x) { return x / (1.f + __expf(-x)); }
// assumed k-slot map for 16x16x32 frags; consistent between A assembly and B packs
// so any hw k-permutation cancels.
__device__ __forceinline__ int fragk(int lane, int j) {
  return ((lane >> 4) << 2) + (j & 3) + ((j >> 2) << 4);
}

// ---------------- pack all weights/biases ----------------
__global__ void pack_W(
    const float* __restrict__ sw1, const float* __restrict__ sb1,
    const float* __restrict__ sw2, const float* __restrict__ sb2,
    const float* __restrict__ sw3, const float* __restrict__ sb3,
    const float* __restrict__ sgam, const float* __restrict__ sbet,
    const float* __restrict__ sgw1, const float* __restrict__ sgb1,
    const float* __restrict__ sgw2, const float* __restrict__ sgb2,
    const float* __restrict__ gw1, const float* __restrict__ gb1,
    const float* __restrict__ gw2, const float* __restrict__ gb2,
    const float* __restrict__ gw3, const float* __restrict__ gb3,
    const float* __restrict__ ggam, const float* __restrict__ gbet,
    const float* __restrict__ ggw1, const float* __restrict__ ggb1,
    const float* __restrict__ ggw2, const float* __restrict__ ggb2,
    unsigned char* __restrict__ ws) {
  int id = blockIdx.x * blockDim.x + threadIdx.x;

  if (id < 30720) {              // B1 fragment groups
    int lane = id & 63; int rest = id >> 6;     // (branch*16+ks)*10+nt
    int nt = rest % 10; int rk = rest / 10;
    int ks = rk & 15; int branch = rk >> 4;
    int col = nt * 16 + (lane & 15);
    short8 o;
#pragma unroll
    for (int j = 0; j < 8; ++j) {
      int k = ks * 32 + fragk(lane, j);
      float w;
      if (branch < 2) {
        if (col < 128) w = gw1[((branch * 2 + (col >> 6)) * 512 + k) * 64 + (col & 63)];
        else           w = ggw1[(branch * 512 + k) * 32 + (col - 128)];
      } else {
        if (col < 128) w = sw1[((col >> 6) * 512 + k) * 64 + (col & 63)];
        else           w = sgw1[k * 32 + (col - 128)];
      }
      o[j] = (short)f2bf(w);
    }
    ((short8*)(ws + OFF_B1))[id] = o;
    return;
  }
  id -= 30720;
  if (id < 1536) {               // B2
    int lane = id & 63; int rest = id >> 6;     // eid*4 + kk*2 + nt
    int nt = rest & 1, kk = (rest >> 1) & 1, eid = rest >> 2;
    int n = nt * 16 + (lane & 15);
    short8 o;
#pragma unroll
    for (int j = 0; j < 8; ++j) {
      int k = kk * 32 + fragk(lane, j);
      float w = (eid < 4) ? gw2[(eid * 64 + k) * 32 + n] : sw2[((eid - 4) * 64 + k) * 32 + n];
      o[j] = (short)f2bf(w);
    }
    ((short8*)(ws + OFF_B2))[id] = o;
    return;
  }
  id -= 1536;
  if (id < 1536) {               // B3
    int lane = id & 63; int rest = id >> 6;     // eid*4 + nt
    int nt = rest & 3, eid = rest >> 2;
    int n = nt * 16 + (lane & 15);
    short8 o;
#pragma unroll
    for (int j = 0; j < 8; ++j) {
      int k = fragk(lane, j);                   // < 32
      float w = (eid < 4) ? gw3[(eid * 32 + k) * 64 + n] : sw3[((eid - 4) * 32 + k) * 64 + n];
      o[j] = (short)f2bf(w);
    }
    ((short8*)(ws + OFF_B3))[id] = o;
    return;
  }
  id -= 1536;
  if (id < 480) {                // b1cat [3][160]
    int branch = id / 160, col = id % 160;
    float w;
    if (col < 128) w = (branch < 2) ? gb1[(branch * 2 + (col >> 6)) * 64 + (col & 63)]
                                    : sb1[(col >> 6) * 64 + (col & 63)];
    else           w = (branch < 2) ? ggb1[branch * 32 + (col - 128)] : sgb1[col - 128];
    ((float*)(ws + OFF_b1))[id] = w;
    return;
  }
  id -= 480;
  if (id < 192) { ((float*)(ws + OFF_b2))[id] = (id < 128) ? gb2[id] : sb2[id - 128]; return; }
  id -= 192;
  if (id < 384) { ((float*)(ws + OFF_b3))[id] = (id < 256) ? gb3[id] : sb3[id - 256]; return; }
  id -= 384;
  if (id < 384) { ((float*)(ws + OFF_gam))[id] = (id < 256) ? ggam[id] : sgam[id - 256]; return; }
  id -= 384;
  if (id < 384) { ((float*)(ws + OFF_bet))[id] = (id < 256) ? gbet[id] : sbet[id - 256]; return; }
  id -= 384;
  if (id < 192) { int branch = id / 64; ((float*)(ws + OFF_gw2))[id] = (branch < 2) ? ggw2[id] : sgw2[id % 64]; return; }
  id -= 192;
  if (id < 6)  { ((float*)(ws + OFF_gb2))[id] = (id < 4) ? ggb2[id] : sgb2[id % 2]; return; }
}

// ---------------- fused main kernel ----------------
// grid (256, 3): blockIdx.x -> 64-row block (4 waves x 16 rows), blockIdx.y -> branch.
// v is read directly (f32->bf16 fragment assembly in-register); B1 is staged per
// k-step in LDS (double-buffered, shared by the block's 4 waves).
__global__ __launch_bounds__(256) void fused_main(const float* __restrict__ v,
                                                  const unsigned char* __restrict__ ws,
                                                  float* __restrict__ out) {
  const int tid  = threadIdx.x;
  const int lane = tid & 63, wave = tid >> 6;
  const int branch = blockIdx.y;
  const int mtile = blockIdx.x * 4 + wave;          // 16-row tile, 0..1023
  const int col16 = lane & 15, g4 = lane >> 4;

  const short8* B1 = (const short8*)(ws + OFF_B1) + branch * 16 * 640;
  const short8* B2 = (const short8*)(ws + OFF_B2);
  const short8* B3 = (const short8*)(ws + OFF_B3);
  const float* b1c  = (const float*)(ws + OFF_b1) + branch * 160;
  const float* b2c  = (const float*)(ws + OFF_b2);
  const float* b3c  = (const float*)(ws + OFF_b3);
  const float* gamc = (const float*)(ws + OFF_gam);
  const float* betc = (const float*)(ws + OFF_bet);
  const float* gw2c = (const float*)(ws + OFF_gw2) + branch * 64;
  const float* gb2c = (const float*)(ws + OFF_gb2) + branch * 2;

  __shared__ short8 b1s[2][640];               // 20 KB double-buffered B1 k-slice
  __shared__ unsigned short h1l[4][16][164];   // padded: conflict-free frag reads
  __shared__ unsigned short h2l[4][16][68];
  __shared__ float gatew[4][16][2];

  // ---- prologue: stage ks=0 slice into buffer 0 ----
  {
    short8 r0 = B1[tid];
    short8 r1 = B1[tid + 256];
    b1s[0][tid] = r0;
    b1s[0][tid + 256] = r1;
    if (tid < 128) b1s[0][tid + 512] = B1[tid + 512];
  }

  // ---- stage 1: [16 x 512] @ [512 x 160] ----
  f32x4 acc[10];
#pragma unroll
  for (int nt = 0; nt < 10; ++nt) acc[nt] = (f32x4){0.f, 0.f, 0.f, 0.f};

  const float* vrow = v + (mtile * 16 + col16) * 512 + (g4 << 2);

  for (int ks = 0; ks < 16; ++ks) {
    const int cur = ks & 1;
    short8 s0, s1, s2;
    if (ks < 15) {                              // issue next-slice global loads
      const short8* src = B1 + (ks + 1) * 640;
      s0 = src[tid];
      s1 = src[tid + 256];
      if (tid < 128) s2 = src[tid + 512];
    }
    __syncthreads();                            // buf[cur] ready; prior readers of buf[cur^1] done
    // A fragment: two float4 loads + f32->bf16 convert
    float4 lo = *(const float4*)(vrow + ks * 32);
    float4 hi = *(const float4*)(vrow + ks * 32 + 16);
    short8 a;
    a[0] = (short)f2bf(lo.x); a[1] = (short)f2bf(lo.y);
    a[2] = (short)f2bf(lo.z); a[3] = (short)f2bf(lo.w);
    a[4] = (short)f2bf(hi.x); a[5] = (short)f2bf(hi.y);
    a[6] = (short)f2bf(hi.z); a[7] = (short)f2bf(hi.w);
#pragma unroll
    for (int nt = 0; nt < 10; ++nt) {
      short8 b = b1s[cur][nt * 64 + lane];
      acc[nt] = __builtin_amdgcn_mfma_f32_16x16x32_bf16(a, b, acc[nt], 0, 0, 0);
    }
    if (ks < 15) {                              // write next slice into other buffer
      const int nxt = cur ^ 1;
      b1s[nxt][tid] = s0;
      b1s[nxt][tid + 256] = s1;
      if (tid < 128) b1s[nxt][tid + 512] = s2;
    }
  }

  // bias + silu -> LDS (bf16), D layout: col=lane&15, row=4*(lane>>4)+reg
#pragma unroll
  for (int nt = 0; nt < 10; ++nt) {
    int col = nt * 16 + col16;
    float bb = b1c[col];
#pragma unroll
    for (int r = 0; r < 4; ++r) {
      int row = (g4 << 2) + r;
      h1l[wave][row][col] = f2bf(silu(acc[nt][r] + bb));
    }
  }
  __syncthreads();

  // ---- gate: logits from silu'd hidden (cols 128..159), softmax over 2 ----
  {
    int rowg = (lane >> 1) & 15;
    int e = lane & 1;
    float logit = gb2c[e];
#pragma unroll 8
    for (int j = 0; j < 32; ++j)
      logit += bf2f(h1l[wave][rowg][128 + j]) * gw2c[j * 2 + e];
    float other = __shfl_xor(logit, 1, 64);
    float mx = fmaxf(logit, other);
    float a0 = __expf(logit - mx), a1 = __expf(other - mx);
    if (lane < 32) gatew[wave][rowg][e] = a0 / (a0 + a1);
  }

  // ---- stage 2: per expert [16 x 64] @ [64 x 32], silu -> LDS ----
#pragma unroll
  for (int e2 = 0; e2 < 2; ++e2) {
    const int eid = (branch < 2) ? branch * 2 + e2 : 4 + e2;
    f32x4 a2[2];
    a2[0] = (f32x4){0.f, 0.f, 0.f, 0.f};
    a2[1] = (f32x4){0.f, 0.f, 0.f, 0.f};
#pragma unroll
    for (int kk = 0; kk < 2; ++kk) {
      const unsigned short* p = &h1l[wave][col16][e2 * 64 + kk * 32 + (g4 << 2)];
      union { short8 s; unsigned u[4]; } af;
      af.u[0] = *(const unsigned*)p;        af.u[1] = *(const unsigned*)(p + 2);
      af.u[2] = *(const unsigned*)(p + 16); af.u[3] = *(const unsigned*)(p + 18);
#pragma unroll
      for (int nt = 0; nt < 2; ++nt) {
        short8 b = B2[((eid * 2 + kk) * 2 + nt) * 64 + lane];
        a2[nt] = __builtin_amdgcn_mfma_f32_16x16x32_bf16(af.s, b, a2[nt], 0, 0, 0);
      }
    }
#pragma unroll
    for (int nt = 0; nt < 2; ++nt) {
      int c2 = nt * 16 + col16;
      float bb = b2c[eid * 32 + c2];
#pragma unroll
      for (int r = 0; r < 4; ++r) {
        int row = (g4 << 2) + r;
        h2l[wave][row][e2 * 32 + c2] = f2bf(silu(a2[nt][r] + bb));
      }
    }
  }
  __syncthreads();

  // ---- stage 3: per expert [16 x 32] @ [32 x 64], LN, gated combine ----
  float z[4][4];
#pragma unroll
  for (int r = 0; r < 4; ++r)
#pragma unroll
    for (int nt = 0; nt < 4; ++nt) z[r][nt] = 0.f;

#pragma unroll
  for (int e2 = 0; e2 < 2; ++e2) {
    const int eid = (branch < 2) ? branch * 2 + e2 : 4 + e2;
    f32x4 a3[4];
#pragma unroll
    for (int nt = 0; nt < 4; ++nt) a3[nt] = (f32x4){0.f, 0.f, 0.f, 0.f};
    const unsigned short* p = &h2l[wave][col16][e2 * 32 + (g4 << 2)];
    union { short8 s; unsigned u[4]; } af;
    af.u[0] = *(const unsigned*)p;        af.u[1] = *(const unsigned*)(p + 2);
    af.u[2] = *(const unsigned*)(p + 16); af.u[3] = *(const unsigned*)(p + 18);
#pragma unroll
    for (int nt = 0; nt < 4; ++nt) {
      short8 b = B3[(eid * 4 + nt) * 64 + lane];
      a3[nt] = __builtin_amdgcn_mfma_f32_16x16x32_bf16(af.s, b, a3[nt], 0, 0, 0);
    }
#pragma unroll
    for (int r = 0; r < 4; ++r) {
      float o[4], s = 0.f, s2 = 0.f;
#pragma unroll
      for (int nt = 0; nt < 4; ++nt) {
        o[nt] = a3[nt][r] + b3c[eid * 64 + nt * 16 + col16];
        s += o[nt]; s2 += o[nt] * o[nt];
      }
#pragma unroll
      for (int m = 1; m < 16; m <<= 1) {
        s  += __shfl_xor(s, m, 64);
        s2 += __shfl_xor(s2, m, 64);
      }
      float mu  = s * 0.015625f;
      float var = s2 * 0.015625f - mu * mu;
      float inv = rsqrtf(var + 1e-5f);
      int row = (g4 << 2) + r;
      float wt = gatew[wave][row][e2];
#pragma unroll
      for (int nt = 0; nt < 4; ++nt) {
        int c = nt * 16 + col16;
        float ln = (o[nt] - mu) * inv * gamc[eid * 64 + c] + betc[eid * 64 + c];
        z[r][nt] += wt * ln;
      }
    }
  }

#pragma unroll
  for (int r = 0; r < 4; ++r) {
    int grow = mtile * 16 + (g4 << 2) + r;
#pragma unroll
    for (int nt = 0; nt < 4; ++nt)
      out[(branch * 16384 + grow) * 64 + nt * 16 + col16] = z[r][nt];
  }
}

extern "C" void kernel_launch(void* const* d_in, const int* in_sizes, int n_in,
                              void* d_out, int out_size, void* d_ws, size_t ws_size,
                              hipStream_t stream) {
  const float* v    = (const float*)d_in[0];
  const float* sw1  = (const float*)d_in[1];
  const float* sb1  = (const float*)d_in[2];
  const float* sw2  = (const float*)d_in[3];
  const float* sb2  = (const float*)d_in[4];
  const float* sw3  = (const float*)d_in[5];
  const float* sb3  = (const float*)d_in[6];
  const float* sgam = (const float*)d_in[7];
  const float* sbet = (const float*)d_in[8];
  const float* sgw1 = (const float*)d_in[9];
  const float* sgb1 = (const float*)d_in[10];
  const float* sgw2 = (const float*)d_in[11];
  const float* sgb2 = (const float*)d_in[12];
  const float* gw1  = (const float*)d_in[13];
  const float* gb1  = (const float*)d_in[14];
  const float* gw2  = (const float*)d_in[15];
  const float* gb2  = (const float*)d_in[16];
  const float* gw3  = (const float*)d_in[17];
  const float* gb3  = (const float*)d_in[18];
  const float* ggam = (const float*)d_in[19];
  const float* gbet = (const float*)d_in[20];
  const float* ggw1 = (const float*)d_in[21];
  const float* ggb1 = (const float*)d_in[22];
  const float* ggw2 = (const float*)d_in[23];
  const float* ggb2 = (const float*)d_in[24];
  unsigned char* ws = (unsigned char*)d_ws;
  float* out = (float*)d_out;

  pack_W<<<dim3(140), dim3(256), 0, stream>>>(
      sw1, sb1, sw2, sb2, sw3, sb3, sgam, sbet, sgw1, sgb1, sgw2, sgb2,
      gw1, gb1, gw2, gb2, gw3, gb3, ggam, gbet, ggw1, ggb1, ggw2, ggb2, ws);
  fused_main<<<dim3(256, 3), dim3(256), 0, stream>>>(v, ws, out);
}